// Round 3
// baseline (1800.011 us; speedup 1.0000x reference)
//
#include <hip/hip_runtime.h>
#include <hip/hip_bf16.h>

// SetTransEncoder: B=64, N=2048, M=32, D=128, H=4, DH=32, DFF=512, L=2
#define BB 64
#define NN 2048
#define MM 32
#define DD 128
#define HH 4
#define DHH 32
#define LFF 512
#define LL 2
#define BN (BB*NN)   // 131072 rows
#define BM (BB*MM)   // 2048 rows

typedef short bf16x8 __attribute__((ext_vector_type(8)));
typedef float f32x4 __attribute__((ext_vector_type(4)));

__device__ __forceinline__ unsigned short f2bf(float f){
  union { float f; unsigned int u; } v; v.f = f;
  unsigned int r = 0x7FFFu + ((v.u >> 16) & 1u);
  return (unsigned short)((v.u + r) >> 16);
}

__device__ __forceinline__ bf16x8 cvt8(const float* __restrict__ p){
  float4 a = *reinterpret_cast<const float4*>(p);
  float4 b = *reinterpret_cast<const float4*>(p + 4);
  bf16x8 r;
  r[0]=(short)f2bf(a.x); r[1]=(short)f2bf(a.y); r[2]=(short)f2bf(a.z); r[3]=(short)f2bf(a.w);
  r[4]=(short)f2bf(b.x); r[5]=(short)f2bf(b.y); r[6]=(short)f2bf(b.z); r[7]=(short)f2bf(b.w);
  return r;
}

// stage 128x128 fp32 W (row stride ldw) into LDS as bf16, transposed [c][k] with
// XOR swizzle on the k 8-group to kill ds_read_b128 bank conflicts.
__device__ __forceinline__ void stage_w128(const float* __restrict__ W, unsigned short* Wt, int ldw){
  for (int i = threadIdx.x; i < 128*128; i += 512){
    int k = i >> 7, c = i & 127;
    Wt[(c << 7) + (k ^ ((c & 7) << 3))] = f2bf(W[k*ldw + c]);
  }
}

__device__ __forceinline__ bf16x8 bfrag(const unsigned short* Wt, int cb, int k0, int lane){
  int c = (cb << 4) + (lane & 15);
  int kk = (k0 + ((lane >> 4) << 3)) ^ ((c & 7) << 3);
  return *reinterpret_cast<const bf16x8*>(Wt + (c << 7) + kk);
}

// per-wave 16x128 tile GEMM over K=128: acc += A[r0..r0+16) @ W (staged in Wt)
__device__ __forceinline__ void gemm_core(const float* __restrict__ A, const unsigned short* Wt,
                                          int r0, int lane, f32x4 acc[8]){
  #pragma unroll
  for (int ks = 0; ks < 4; ks++){
    const float* ap = A + (size_t)(r0 + (lane & 15)) * 128 + ks*32 + ((lane >> 4) << 3);
    bf16x8 a = cvt8(ap);
    #pragma unroll
    for (int cb = 0; cb < 8; cb++)
      acc[cb] = __builtin_amdgcn_mfma_f32_16x16x32_bf16(a, bfrag(Wt, cb, ks*32, lane), acc[cb], 0, 0, 0);
  }
}

// epilogue: v = acc + bias + resid; LayerNorm over the 128-wide row; store fp32.
// MFMA C layout: col = cb*16 + (lane&15), row = r0 + 4*(lane>>4) + reg.
__device__ __forceinline__ void ln_epilogue(f32x4 acc[8], const float* __restrict__ bias,
    const float* __restrict__ resid, unsigned int resmask,
    const float* __restrict__ g, const float* __restrict__ beta,
    float* __restrict__ C, int r0, int lane){
  int li = lane & 15, lg = lane >> 4;
  float gv[8], bv[8], biasv[8];
  #pragma unroll
  for (int cb = 0; cb < 8; cb++){
    int col = cb*16 + li;
    gv[cb] = g[col]; bv[cb] = beta[col];
    biasv[cb] = bias ? bias[col] : 0.f;
  }
  #pragma unroll
  for (int q = 0; q < 4; q++){
    int r = r0 + lg*4 + q;
    const float* rrow = resid + (size_t)(r & resmask) * 128;
    float v[8], sum = 0.f, ss = 0.f;
    #pragma unroll
    for (int cb = 0; cb < 8; cb++){
      float x = acc[cb][q] + biasv[cb] + rrow[cb*16 + li];
      v[cb] = x; sum += x; ss += x*x;
    }
    #pragma unroll
    for (int mk = 1; mk < 16; mk <<= 1){ sum += __shfl_xor(sum, mk); ss += __shfl_xor(ss, mk); }
    float mu = sum * (1.f/128.f);
    float var = ss * (1.f/128.f) - mu*mu;
    float rs = rsqrtf(var + 1e-5f);
    float* crow = C + (size_t)r * 128;
    #pragma unroll
    for (int cb = 0; cb < 8; cb++)
      crow[cb*16 + li] = (v[cb] - mu) * rs * gv[cb] + bv[cb];
  }
}

// ---------------- kernels ----------------

// C[rows x 128] = A[rows x 128] @ W[128 x 128]
__global__ __launch_bounds__(512) void gemm128_plain(const float* __restrict__ A,
    const float* __restrict__ W, float* __restrict__ C, int rows){
  __shared__ __align__(16) unsigned short Wt[128*128];
  stage_w128(W, Wt, 128);
  __syncthreads();
  int lane = threadIdx.x & 63, wave = threadIdx.x >> 6;
  int r0 = blockIdx.x*128 + wave*16;
  f32x4 acc[8];
  #pragma unroll
  for (int cb = 0; cb < 8; cb++) acc[cb] = (f32x4){0.f,0.f,0.f,0.f};
  gemm_core(A, Wt, r0, lane, acc);
  int li = lane & 15, lg = lane >> 4;
  #pragma unroll
  for (int q = 0; q < 4; q++){
    float* crow = C + (size_t)(r0 + lg*4 + q) * 128;
    #pragma unroll
    for (int cb = 0; cb < 8; cb++) crow[cb*16 + li] = acc[cb][q];
  }
}

// C = LayerNorm(resid + A @ W (+bias)) * g + beta
__global__ __launch_bounds__(512) void gemm128_ln(const float* __restrict__ A,
    const float* __restrict__ W, const float* __restrict__ bias,
    const float* __restrict__ resid, unsigned int resmask,
    const float* __restrict__ g, const float* __restrict__ beta,
    float* __restrict__ C, int rows){
  __shared__ __align__(16) unsigned short Wt[128*128];
  stage_w128(W, Wt, 128);
  __syncthreads();
  int lane = threadIdx.x & 63, wave = threadIdx.x >> 6;
  int r0 = blockIdx.x*128 + wave*16;
  f32x4 acc[8];
  #pragma unroll
  for (int cb = 0; cb < 8; cb++) acc[cb] = (f32x4){0.f,0.f,0.f,0.f};
  gemm_core(A, Wt, r0, lane, acc);
  ln_epilogue(acc, bias, resid, resmask, g, beta, C, r0, lane);
}

// prep: Qi = I @ Wq  (32x128), then Wf[k][c] = scale * sum_{d<32} Wk[k][hc*32+d]*Qi[qc][hc*32+d]
// so that  x @ Wf == scores^T laid out [b, key, h*32+q]   (folds K-projection + QK^T)
__global__ __launch_bounds__(256) void prep_phaseA(const float* __restrict__ I,
    const float* __restrict__ Wq, const float* __restrict__ Wk, float* __restrict__ Wf){
  __shared__ float Qi[32*128];
  for (int i = threadIdx.x; i < 4096; i += 256){
    int q = i >> 7, c = i & 127;
    float s = 0.f;
    #pragma unroll 8
    for (int d = 0; d < 128; d++) s += I[q*128 + d] * Wq[d*128 + c];
    Qi[i] = s;
  }
  __syncthreads();
  const float scale = 0.17677669529663687f; // 1/sqrt(32)
  for (int i = threadIdx.x; i < 16384; i += 256){
    int k = i >> 7, c = i & 127;
    int hc = c >> 5, qc = c & 31;
    float s = 0.f;
    #pragma unroll 8
    for (int d = 0; d < 32; d++) s += Wk[k*128 + hc*32 + d] * Qi[qc*128 + hc*32 + d];
    Wf[i] = s * scale;
  }
}

// induced attention: column softmax over St[b, j, h*32+q] (j = 0..2047) fused with PV.
// grid = B*H blocks, 256 threads = 32 q-lanes x 8 key-groups. Online softmax, LDS combine.
__global__ __launch_bounds__(256) void attn_ind(const float* __restrict__ St,
    const float* __restrict__ V, float* __restrict__ O){
  int b = blockIdx.x >> 2, h = blockIdx.x & 3;
  int q = threadIdx.x & 31;
  int gg = threadIdx.x >> 5;
  int lane = threadIdx.x & 63;
  int wave = threadIdx.x >> 6;
  float m = -1e30f, s = 0.f;
  float o[32];
  #pragma unroll
  for (int d = 0; d < 32; d++) o[d] = 0.f;
  const float* Sb = St + (size_t)b*NN*128 + h*32 + q;
  const float* Vb = V  + (size_t)b*NN*128 + h*32;
  for (int j = gg; j < NN; j += 8){
    float sv = Sb[(size_t)j*128];
    float p;
    if (sv > m){
      float f = __expf(m - sv);
      s *= f;
      #pragma unroll
      for (int d = 0; d < 32; d++) o[d] *= f;
      m = sv; p = 1.f;
    } else {
      p = __expf(sv - m);
    }
    s += p;
    const float4* vr = reinterpret_cast<const float4*>(Vb + (size_t)j*128);
    #pragma unroll
    for (int d4 = 0; d4 < 8; d4++){
      float4 vv = vr[d4];
      o[d4*4+0] += p*vv.x; o[d4*4+1] += p*vv.y; o[d4*4+2] += p*vv.z; o[d4*4+3] += p*vv.w;
    }
  }
  { // combine the two key-groups in this wave (lanes xor 32)
    float m2 = __shfl_xor(m, 32);
    float s2 = __shfl_xor(s, 32);
    float mn = fmaxf(m, m2);
    float f1 = __expf(m - mn), f2 = __expf(m2 - mn);
    s = s*f1 + s2*f2;
    #pragma unroll
    for (int d = 0; d < 32; d++){
      float o2 = __shfl_xor(o[d], 32);
      o[d] = o[d]*f1 + o2*f2;
    }
    m = mn;
  }
  __shared__ float red[4][32][34];
  if (lane < 32){
    red[wave][q][0] = m;
    red[wave][q][1] = s;
    #pragma unroll
    for (int d = 0; d < 32; d++) red[wave][q][2+d] = o[d];
  }
  __syncthreads();
  if (threadIdx.x < 32){
    int qq = threadIdx.x;
    float mm = red[0][qq][0], ssum = red[0][qq][1];
    float oo[32];
    #pragma unroll
    for (int d = 0; d < 32; d++) oo[d] = red[0][qq][2+d];
    for (int w = 1; w < 4; w++){
      float m2 = red[w][qq][0], s2 = red[w][qq][1];
      float mn = fmaxf(mm, m2);
      float f1 = __expf(mm - mn), f2 = __expf(m2 - mn);
      ssum = ssum*f1 + s2*f2;
      #pragma unroll
      for (int d = 0; d < 32; d++) oo[d] = oo[d]*f1 + red[w][qq][2+d]*f2;
      mm = mn;
    }
    float inv = 1.f / ssum;
    float* op = O + (size_t)(b*MM + qq)*128 + h*32;
    #pragma unroll
    for (int d = 0; d < 32; d++) op[d] = oo[d]*inv;
  }
}

// set-side attention: 2048 queries x 32 keys per (b,h); one thread per (q,h) row.
// K/V staged in LDS with h-rotated float4 slots to avoid 4-way bank conflicts.
__global__ __launch_bounds__(256) void attn_b(const float* __restrict__ Q,
    const float* __restrict__ Kh, const float* __restrict__ Vh, float* __restrict__ O){
  __shared__ __align__(16) float Ks[4096];
  __shared__ __align__(16) float Vs[4096];
  int b = blockIdx.x >> 5;
  int t = ((blockIdx.x & 31) << 8) + threadIdx.x;
  int q = t >> 2, h = t & 3;
  for (int i = threadIdx.x; i < 4096; i += 256){
    int k = i >> 7, rem = i & 127, hh = rem >> 5, d = rem & 31;
    int sidx = (k << 7) + (hh << 5) + ((((d >> 2) + hh) & 7) << 2) + (d & 3);
    Ks[sidx] = Kh[b*4096 + i];
    Vs[sidx] = Vh[b*4096 + i];
  }
  __syncthreads();
  const float* qp = Q + (size_t)(b*NN + q)*128 + h*32;
  float qr[32];
  #pragma unroll
  for (int j = 0; j < 8; j++){
    float4 f = reinterpret_cast<const float4*>(qp)[j];
    qr[4*j]=f.x; qr[4*j+1]=f.y; qr[4*j+2]=f.z; qr[4*j+3]=f.w;
  }
  const float scale = 0.17677669529663687f;
  float sc[32]; float m = -1e30f;
  #pragma unroll
  for (int k = 0; k < 32; k++){
    float dot = 0.f;
    #pragma unroll
    for (int j = 0; j < 8; j++){
      const float4 kv = *reinterpret_cast<const float4*>(&Ks[(k<<7)+(h<<5)+(((j+h)&7)<<2)]);
      dot += qr[4*j]*kv.x + qr[4*j+1]*kv.y + qr[4*j+2]*kv.z + qr[4*j+3]*kv.w;
    }
    sc[k] = dot*scale;
    m = fmaxf(m, sc[k]);
  }
  float den = 0.f;
  #pragma unroll
  for (int k = 0; k < 32; k++){ sc[k] = __expf(sc[k]-m); den += sc[k]; }
  float inv = 1.f/den;
  float o[32];
  #pragma unroll
  for (int d = 0; d < 32; d++) o[d] = 0.f;
  #pragma unroll
  for (int k = 0; k < 32; k++){
    float p = sc[k];
    #pragma unroll
    for (int j = 0; j < 8; j++){
      const float4 vv = *reinterpret_cast<const float4*>(&Vs[(k<<7)+(h<<5)+(((j+h)&7)<<2)]);
      o[4*j] += p*vv.x; o[4*j+1] += p*vv.y; o[4*j+2] += p*vv.z; o[4*j+3] += p*vv.w;
    }
  }
  float* op = O + (size_t)(b*NN + q)*128 + h*32;
  #pragma unroll
  for (int j = 0; j < 8; j++){
    float4 f; f.x=o[4*j]*inv; f.y=o[4*j+1]*inv; f.z=o[4*j+2]*inv; f.w=o[4*j+3]*inv;
    reinterpret_cast<float4*>(op)[j] = f;
  }
}

// fused FFN: OUT = LN(X + relu(X@W1+b1)@W2 + b2), DFF chunked by 128 through LDS.
__global__ __launch_bounds__(512) void ffn_fused(const float* __restrict__ X,
    const float* __restrict__ W1, const float* __restrict__ b1,
    const float* __restrict__ W2, const float* __restrict__ b2,
    const float* __restrict__ g, const float* __restrict__ beta,
    float* __restrict__ OUT, int rows){
  __shared__ __align__(16) unsigned short Wt[128*128];
  __shared__ __align__(16) unsigned short ht[128*128];
  int lane = threadIdx.x & 63, wave = threadIdx.x >> 6;
  int li = lane & 15, lg = lane >> 4;
  int r0 = blockIdx.x*128 + wave*16;
  f32x4 accO[8];
  #pragma unroll
  for (int cb = 0; cb < 8; cb++) accO[cb] = (f32x4){0.f,0.f,0.f,0.f};
  for (int dc = 0; dc < 4; dc++){
    __syncthreads();                       // protect Wt/ht from previous iteration readers
    stage_w128(W1 + dc*128, Wt, 512);      // W1[k][dc*128 + c]
    __syncthreads();
    f32x4 acc1[8];
    #pragma unroll
    for (int cb = 0; cb < 8; cb++) acc1[cb] = (f32x4){0.f,0.f,0.f,0.f};
    gemm_core(X, Wt, r0, lane, acc1);
    #pragma unroll
    for (int q = 0; q < 4; q++){
      int rl = wave*16 + lg*4 + q;
      #pragma unroll
      for (int cb = 0; cb < 8; cb++){
        int col = cb*16 + li;
        float v = acc1[cb][q] + b1[dc*128 + col];
        v = fmaxf(v, 0.f);
        ht[(rl << 7) + (col ^ ((rl & 7) << 3))] = f2bf(v);
      }
    }
    __syncthreads();
    stage_w128(W2 + dc*128*128, Wt, 128);  // W2[dc*128 + k][c]
    __syncthreads();
    #pragma unroll
    for (int ks = 0; ks < 4; ks++){
      int rl = wave*16 + li;
      int kk = (ks*32 + (lg << 3)) ^ ((rl & 7) << 3);
      bf16x8 a = *reinterpret_cast<const bf16x8*>(ht + (rl << 7) + kk);
      #pragma unroll
      for (int cb = 0; cb < 8; cb++)
        accO[cb] = __builtin_amdgcn_mfma_f32_16x16x32_bf16(a, bfrag(Wt, cb, ks*32, lane), accO[cb], 0, 0, 0);
    }
  }
  ln_epilogue(accO, b2, X, 0xFFFFFFFFu, g, beta, OUT, r0, lane);
}

extern "C" void kernel_launch(void* const* d_in, const int* in_sizes, int n_in,
                              void* d_out, int out_size, void* d_ws, size_t ws_size,
                              hipStream_t stream){
  (void)in_sizes; (void)n_in; (void)out_size; (void)ws_size;
  const float* feat = (const float*)d_in[0];
  const float* Ipts = (const float*)d_in[1];
  const float* Wq   = (const float*)d_in[2];
  const float* Wk   = (const float*)d_in[3];
  const float* Wv   = (const float*)d_in[4];
  const float* Wo   = (const float*)d_in[5];
  const float* W1   = (const float*)d_in[6];
  const float* b1   = (const float*)d_in[7];
  const float* W2   = (const float*)d_in[8];
  const float* b2   = (const float*)d_in[9];
  const float* g1   = (const float*)d_in[10];
  const float* be1  = (const float*)d_in[11];
  const float* g2   = (const float*)d_in[12];
  const float* be2  = (const float*)d_in[13];
  float* out = (float*)d_out;

  float* bigA   = (float*)d_ws;                 // 64 MiB: St (A) / Q,x1 (B)
  float* bigB   = bigA + (size_t)BN*128;        // 64 MiB: V (A) / attn-out (B)
  float* wfused = bigB + (size_t)BN*128;        // 16384
  float* Oind   = wfused + 16384;               // BM*128
  float* x1ind  = Oind   + BM*128;
  float* Hind   = x1ind  + BM*128;
  float* Khb    = Hind   + BM*128;
  float* Vhb    = Khb    + BM*128;

  for (int l = 0; l < LL; l++){
    const float* x = (l == 0) ? feat : out;
    const float* Il = Ipts + l*MM*DD;
    int j0 = l*2, j1 = l*2 + 1;
    // ---- phase A: H = MAB(I, x) ----
    prep_phaseA<<<1, 256, 0, stream>>>(Il, Wq + j0*16384, Wk + j0*16384, wfused);
    gemm128_plain<<<BN/128, 512, 0, stream>>>(x, wfused, bigA, BN);          // St = x @ Wf
    gemm128_plain<<<BN/128, 512, 0, stream>>>(x, Wv + j0*16384, bigB, BN);   // V
    attn_ind<<<BB*HH, 256, 0, stream>>>(bigA, bigB, Oind);
    gemm128_ln<<<BM/128, 512, 0, stream>>>(Oind, Wo + j0*16384, nullptr, Il, 31u,
                                           g1 + j0*128, be1 + j0*128, x1ind, BM);
    ffn_fused<<<BM/128, 512, 0, stream>>>(x1ind, W1 + j0*65536, b1 + j0*512,
                                          W2 + j0*65536, b2 + j0*128,
                                          g2 + j0*128, be2 + j0*128, Hind, BM);
    // ---- phase B: x = MAB(x, H) ----
    gemm128_plain<<<BN/128, 512, 0, stream>>>(x, Wq + j1*16384, bigA, BN);   // Q
    gemm128_plain<<<BM/128, 512, 0, stream>>>(Hind, Wk + j1*16384, Khb, BM);
    gemm128_plain<<<BM/128, 512, 0, stream>>>(Hind, Wv + j1*16384, Vhb, BM);
    attn_b<<<BB*32, 256, 0, stream>>>(bigA, Khb, Vhb, bigB);
    gemm128_ln<<<BN/128, 512, 0, stream>>>(bigB, Wo + j1*16384, nullptr, x, (unsigned)(BN-1),
                                           g1 + j1*128, be1 + j1*128, bigA, BN);
    ffn_fused<<<BN/128, 512, 0, stream>>>(bigA, W1 + j1*65536, b1 + j1*512,
                                          W2 + j1*65536, b2 + j1*128,
                                          g2 + j1*128, be2 + j1*128, out, BN);
  }
}

// Round 4
// 1341.699 us; speedup vs baseline: 1.3416x; 1.3416x over previous
//
#include <hip/hip_runtime.h>
#include <hip/hip_bf16.h>

// SetTransEncoder: B=64, N=2048, M=32, D=128, H=4, DH=32, DFF=512, L=2
#define BB 64
#define NN 2048
#define MM 32
#define DD 128
#define HH 4
#define DHH 32
#define LFF 512
#define LL 2
#define BN (BB*NN)   // 131072 rows
#define BM (BB*MM)   // 2048 rows

typedef short bf16x8 __attribute__((ext_vector_type(8)));
typedef float f32x4 __attribute__((ext_vector_type(4)));

__device__ __forceinline__ unsigned short f2bf(float f){
  union { float f; unsigned int u; } v; v.f = f;
  unsigned int r = 0x7FFFu + ((v.u >> 16) & 1u);
  return (unsigned short)((v.u + r) >> 16);
}

__device__ __forceinline__ bf16x8 cvt8(const float* __restrict__ p){
  float4 a = *reinterpret_cast<const float4*>(p);
  float4 b = *reinterpret_cast<const float4*>(p + 4);
  bf16x8 r;
  r[0]=(short)f2bf(a.x); r[1]=(short)f2bf(a.y); r[2]=(short)f2bf(a.z); r[3]=(short)f2bf(a.w);
  r[4]=(short)f2bf(b.x); r[5]=(short)f2bf(b.y); r[6]=(short)f2bf(b.z); r[7]=(short)f2bf(b.w);
  return r;
}

// stage 128x128 fp32 W (row stride ldw) into LDS as bf16, transposed [c][k] with
// XOR swizzle on the k 8-group to kill ds_read_b128 bank conflicts.
__device__ __forceinline__ void stage_w128(const float* __restrict__ W, unsigned short* Wt, int ldw){
  for (int i = threadIdx.x; i < 128*128; i += 512){
    int k = i >> 7, c = i & 127;
    Wt[(c << 7) + (k ^ ((c & 7) << 3))] = f2bf(W[k*ldw + c]);
  }
}

__device__ __forceinline__ bf16x8 bfrag(const unsigned short* Wt, int cb, int k0, int lane){
  int c = (cb << 4) + (lane & 15);
  int kk = (k0 + ((lane >> 4) << 3)) ^ ((c & 7) << 3);
  return *reinterpret_cast<const bf16x8*>(Wt + (c << 7) + kk);
}

// per-wave 16x128 tile GEMM over K=128: acc += A[r0..r0+16) @ W (staged in Wt)
__device__ __forceinline__ void gemm_core(const float* __restrict__ A, const unsigned short* Wt,
                                          int r0, int lane, f32x4 acc[8]){
  #pragma unroll
  for (int ks = 0; ks < 4; ks++){
    const float* ap = A + (size_t)(r0 + (lane & 15)) * 128 + ks*32 + ((lane >> 4) << 3);
    bf16x8 a = cvt8(ap);
    #pragma unroll
    for (int cb = 0; cb < 8; cb++)
      acc[cb] = __builtin_amdgcn_mfma_f32_16x16x32_bf16(a, bfrag(Wt, cb, ks*32, lane), acc[cb], 0, 0, 0);
  }
}

// epilogue: v = acc + bias + resid; LayerNorm over the 128-wide row; store fp32.
// MFMA C layout: col = cb*16 + (lane&15), row = r0 + 4*(lane>>4) + reg.
__device__ __forceinline__ void ln_epilogue(f32x4 acc[8], const float* __restrict__ bias,
    const float* __restrict__ resid, unsigned int resmask,
    const float* __restrict__ g, const float* __restrict__ beta,
    float* __restrict__ C, int r0, int lane){
  int li = lane & 15, lg = lane >> 4;
  float gv[8], bv[8], biasv[8];
  #pragma unroll
  for (int cb = 0; cb < 8; cb++){
    int col = cb*16 + li;
    gv[cb] = g[col]; bv[cb] = beta[col];
    biasv[cb] = bias ? bias[col] : 0.f;
  }
  #pragma unroll
  for (int q = 0; q < 4; q++){
    int r = r0 + lg*4 + q;
    const float* rrow = resid + (size_t)(r & resmask) * 128;
    float v[8], sum = 0.f, ss = 0.f;
    #pragma unroll
    for (int cb = 0; cb < 8; cb++){
      float x = acc[cb][q] + biasv[cb] + rrow[cb*16 + li];
      v[cb] = x; sum += x; ss += x*x;
    }
    #pragma unroll
    for (int mk = 1; mk < 16; mk <<= 1){ sum += __shfl_xor(sum, mk); ss += __shfl_xor(ss, mk); }
    float mu = sum * (1.f/128.f);
    float var = ss * (1.f/128.f) - mu*mu;
    float rs = rsqrtf(var + 1e-5f);
    float* crow = C + (size_t)r * 128;
    #pragma unroll
    for (int cb = 0; cb < 8; cb++)
      crow[cb*16 + li] = (v[cb] - mu) * rs * gv[cb] + bv[cb];
  }
}

// ---------------- kernels ----------------

// C[rows x 128] = A[rows x 128] @ W[128 x 128]
__global__ __launch_bounds__(512) void gemm128_plain(const float* __restrict__ A,
    const float* __restrict__ W, float* __restrict__ C, int rows){
  __shared__ __align__(16) unsigned short Wt[128*128];
  stage_w128(W, Wt, 128);
  __syncthreads();
  int lane = threadIdx.x & 63, wave = threadIdx.x >> 6;
  int r0 = blockIdx.x*128 + wave*16;
  f32x4 acc[8];
  #pragma unroll
  for (int cb = 0; cb < 8; cb++) acc[cb] = (f32x4){0.f,0.f,0.f,0.f};
  gemm_core(A, Wt, r0, lane, acc);
  int li = lane & 15, lg = lane >> 4;
  #pragma unroll
  for (int q = 0; q < 4; q++){
    float* crow = C + (size_t)(r0 + lg*4 + q) * 128;
    #pragma unroll
    for (int cb = 0; cb < 8; cb++) crow[cb*16 + li] = acc[cb][q];
  }
}

// C = LayerNorm(resid + A @ W (+bias)) * g + beta
__global__ __launch_bounds__(512) void gemm128_ln(const float* __restrict__ A,
    const float* __restrict__ W, const float* __restrict__ bias,
    const float* __restrict__ resid, unsigned int resmask,
    const float* __restrict__ g, const float* __restrict__ beta,
    float* __restrict__ C, int rows){
  __shared__ __align__(16) unsigned short Wt[128*128];
  stage_w128(W, Wt, 128);
  __syncthreads();
  int lane = threadIdx.x & 63, wave = threadIdx.x >> 6;
  int r0 = blockIdx.x*128 + wave*16;
  f32x4 acc[8];
  #pragma unroll
  for (int cb = 0; cb < 8; cb++) acc[cb] = (f32x4){0.f,0.f,0.f,0.f};
  gemm_core(A, Wt, r0, lane, acc);
  ln_epilogue(acc, bias, resid, resmask, g, beta, C, r0, lane);
}

// prep: Qi = I @ Wq  (32x128), then Wf[k][c] = scale * sum_{d<32} Wk[k][hc*32+d]*Qi[qc][hc*32+d]
// so that  x @ Wf == scores^T laid out [b, key, h*32+q]   (folds K-projection + QK^T)
__global__ __launch_bounds__(256) void prep_phaseA(const float* __restrict__ I,
    const float* __restrict__ Wq, const float* __restrict__ Wk, float* __restrict__ Wf){
  __shared__ float Qi[32*128];
  for (int i = threadIdx.x; i < 4096; i += 256){
    int q = i >> 7, c = i & 127;
    float s = 0.f;
    #pragma unroll 8
    for (int d = 0; d < 128; d++) s += I[q*128 + d] * Wq[d*128 + c];
    Qi[i] = s;
  }
  __syncthreads();
  const float scale = 0.17677669529663687f; // 1/sqrt(32)
  for (int i = threadIdx.x; i < 16384; i += 256){
    int k = i >> 7, c = i & 127;
    int hc = c >> 5, qc = c & 31;
    float s = 0.f;
    #pragma unroll 8
    for (int d = 0; d < 32; d++) s += Wk[k*128 + hc*32 + d] * Qi[qc*128 + hc*32 + d];
    Wf[i] = s * scale;
  }
}

// induced attention: column softmax over St[b, j, h*32+q] (j = 0..2047) fused with PV.
// grid = B*H blocks, 1024 threads = 32 q-lanes x 32 key-groups (16 waves/CU).
// Online softmax per thread, xor-32 wave combine, 16-wave LDS combine.
__global__ __launch_bounds__(1024) void attn_ind(const float* __restrict__ St,
    const float* __restrict__ V, float* __restrict__ O){
  int b = blockIdx.x >> 2, h = blockIdx.x & 3;
  int q = threadIdx.x & 31;
  int gg = threadIdx.x >> 5;   // 0..31 key-groups
  int lane = threadIdx.x & 63;
  int wave = threadIdx.x >> 6; // 0..15
  float m = -1e30f, s = 0.f;
  float o[32];
  #pragma unroll
  for (int d = 0; d < 32; d++) o[d] = 0.f;
  const float* Sb = St + (size_t)b*NN*128 + h*32 + q;
  const float* Vb = V  + (size_t)b*NN*128 + h*32;
  for (int j = gg; j < NN; j += 32){
    float sv = Sb[(size_t)j*128];
    float p;
    if (sv > m){
      float f = __expf(m - sv);
      s *= f;
      #pragma unroll
      for (int d = 0; d < 32; d++) o[d] *= f;
      m = sv; p = 1.f;
    } else {
      p = __expf(sv - m);
    }
    s += p;
    const float4* vr = reinterpret_cast<const float4*>(Vb + (size_t)j*128);
    #pragma unroll
    for (int d4 = 0; d4 < 8; d4++){
      float4 vv = vr[d4];
      o[d4*4+0] += p*vv.x; o[d4*4+1] += p*vv.y; o[d4*4+2] += p*vv.z; o[d4*4+3] += p*vv.w;
    }
  }
  { // combine the two key-groups in this wave (lanes xor 32)
    float m2 = __shfl_xor(m, 32);
    float s2 = __shfl_xor(s, 32);
    float mn = fmaxf(m, m2);
    float f1 = __expf(m - mn), f2 = __expf(m2 - mn);
    s = s*f1 + s2*f2;
    #pragma unroll
    for (int d = 0; d < 32; d++){
      float o2 = __shfl_xor(o[d], 32);
      o[d] = o[d]*f1 + o2*f2;
    }
    m = mn;
  }
  __shared__ float red[16][32][34];
  if (lane < 32){
    red[wave][q][0] = m;
    red[wave][q][1] = s;
    #pragma unroll
    for (int d = 0; d < 32; d++) red[wave][q][2+d] = o[d];
  }
  __syncthreads();
  if (threadIdx.x < 32){
    int qq = threadIdx.x;
    float mm = red[0][qq][0], ssum = red[0][qq][1];
    float oo[32];
    #pragma unroll
    for (int d = 0; d < 32; d++) oo[d] = red[0][qq][2+d];
    for (int w = 1; w < 16; w++){
      float m2 = red[w][qq][0], s2 = red[w][qq][1];
      float mn = fmaxf(mm, m2);
      float f1 = __expf(mm - mn), f2 = __expf(m2 - mn);
      ssum = ssum*f1 + s2*f2;
      #pragma unroll
      for (int d = 0; d < 32; d++) oo[d] = oo[d]*f1 + red[w][qq][2+d]*f2;
      mm = mn;
    }
    float inv = 1.f / ssum;
    float* op = O + (size_t)(b*MM + qq)*128 + h*32;
    #pragma unroll
    for (int d = 0; d < 32; d++) op[d] = oo[d]*inv;
  }
}

// set-side attention: 2048 queries x 32 keys per (b,h); one thread per (q,h) row.
// K/V staged in LDS with h-rotated float4 slots to avoid 4-way bank conflicts.
__global__ __launch_bounds__(256) void attn_b(const float* __restrict__ Q,
    const float* __restrict__ Kh, const float* __restrict__ Vh, float* __restrict__ O){
  __shared__ __align__(16) float Ks[4096];
  __shared__ __align__(16) float Vs[4096];
  int b = blockIdx.x >> 5;
  int t = ((blockIdx.x & 31) << 8) + threadIdx.x;
  int q = t >> 2, h = t & 3;
  for (int i = threadIdx.x; i < 4096; i += 256){
    int k = i >> 7, rem = i & 127, hh = rem >> 5, d = rem & 31;
    int sidx = (k << 7) + (hh << 5) + ((((d >> 2) + hh) & 7) << 2) + (d & 3);
    Ks[sidx] = Kh[b*4096 + i];
    Vs[sidx] = Vh[b*4096 + i];
  }
  __syncthreads();
  const float* qp = Q + (size_t)(b*NN + q)*128 + h*32;
  float qr[32];
  #pragma unroll
  for (int j = 0; j < 8; j++){
    float4 f = reinterpret_cast<const float4*>(qp)[j];
    qr[4*j]=f.x; qr[4*j+1]=f.y; qr[4*j+2]=f.z; qr[4*j+3]=f.w;
  }
  const float scale = 0.17677669529663687f;
  float sc[32]; float m = -1e30f;
  #pragma unroll
  for (int k = 0; k < 32; k++){
    float dot = 0.f;
    #pragma unroll
    for (int j = 0; j < 8; j++){
      const float4 kv = *reinterpret_cast<const float4*>(&Ks[(k<<7)+(h<<5)+(((j+h)&7)<<2)]);
      dot += qr[4*j]*kv.x + qr[4*j+1]*kv.y + qr[4*j+2]*kv.z + qr[4*j+3]*kv.w;
    }
    sc[k] = dot*scale;
    m = fmaxf(m, sc[k]);
  }
  float den = 0.f;
  #pragma unroll
  for (int k = 0; k < 32; k++){ sc[k] = __expf(sc[k]-m); den += sc[k]; }
  float inv = 1.f/den;
  float o[32];
  #pragma unroll
  for (int d = 0; d < 32; d++) o[d] = 0.f;
  #pragma unroll
  for (int k = 0; k < 32; k++){
    float p = sc[k];
    #pragma unroll
    for (int j = 0; j < 8; j++){
      const float4 vv = *reinterpret_cast<const float4*>(&Vs[(k<<7)+(h<<5)+(((j+h)&7)<<2)]);
      o[4*j] += p*vv.x; o[4*j+1] += p*vv.y; o[4*j+2] += p*vv.z; o[4*j+3] += p*vv.w;
    }
  }
  float* op = O + (size_t)(b*NN + q)*128 + h*32;
  #pragma unroll
  for (int j = 0; j < 8; j++){
    float4 f; f.x=o[4*j]*inv; f.y=o[4*j+1]*inv; f.z=o[4*j+2]*inv; f.w=o[4*j+3]*inv;
    reinterpret_cast<float4*>(op)[j] = f;
  }
}

// fused FFN: OUT = LN(X + relu(X@W1+b1)@W2 + b2), DFF chunked by 128 through LDS.
// A-fragments of X are loaded ONCE into registers and reused across the 4 chunks.
__global__ __launch_bounds__(512) void ffn_fused(const float* __restrict__ X,
    const float* __restrict__ W1, const float* __restrict__ b1,
    const float* __restrict__ W2, const float* __restrict__ b2,
    const float* __restrict__ g, const float* __restrict__ beta,
    float* __restrict__ OUT, int rows){
  __shared__ __align__(16) unsigned short Wt[128*128];
  __shared__ __align__(16) unsigned short ht[128*128];
  int lane = threadIdx.x & 63, wave = threadIdx.x >> 6;
  int li = lane & 15, lg = lane >> 4;
  int r0 = blockIdx.x*128 + wave*16;
  // hoist A fragments (X rows r0..r0+16, all K) into registers
  bf16x8 afrag[4];
  {
    const float* ap0 = X + (size_t)(r0 + li) * 128 + (lg << 3);
    #pragma unroll
    for (int ks = 0; ks < 4; ks++) afrag[ks] = cvt8(ap0 + ks*32);
  }
  f32x4 accO[8];
  #pragma unroll
  for (int cb = 0; cb < 8; cb++) accO[cb] = (f32x4){0.f,0.f,0.f,0.f};
  for (int dc = 0; dc < 4; dc++){
    __syncthreads();                       // protect Wt/ht from previous iteration readers
    stage_w128(W1 + dc*128, Wt, 512);      // W1[k][dc*128 + c]
    __syncthreads();
    f32x4 acc1[8];
    #pragma unroll
    for (int cb = 0; cb < 8; cb++) acc1[cb] = (f32x4){0.f,0.f,0.f,0.f};
    #pragma unroll
    for (int ks = 0; ks < 4; ks++){
      #pragma unroll
      for (int cb = 0; cb < 8; cb++)
        acc1[cb] = __builtin_amdgcn_mfma_f32_16x16x32_bf16(afrag[ks], bfrag(Wt, cb, ks*32, lane), acc1[cb], 0, 0, 0);
    }
    #pragma unroll
    for (int q = 0; q < 4; q++){
      int rl = wave*16 + lg*4 + q;
      #pragma unroll
      for (int cb = 0; cb < 8; cb++){
        int col = cb*16 + li;
        float v = acc1[cb][q] + b1[dc*128 + col];
        v = fmaxf(v, 0.f);
        ht[(rl << 7) + (col ^ ((rl & 7) << 3))] = f2bf(v);
      }
    }
    __syncthreads();
    stage_w128(W2 + dc*128*128, Wt, 128);  // W2[dc*128 + k][c]
    __syncthreads();
    #pragma unroll
    for (int ks = 0; ks < 4; ks++){
      int rl = wave*16 + li;
      int kk = (ks*32 + (lg << 3)) ^ ((rl & 7) << 3);
      bf16x8 a = *reinterpret_cast<const bf16x8*>(ht + (rl << 7) + kk);
      #pragma unroll
      for (int cb = 0; cb < 8; cb++)
        accO[cb] = __builtin_amdgcn_mfma_f32_16x16x32_bf16(a, bfrag(Wt, cb, ks*32, lane), accO[cb], 0, 0, 0);
    }
  }
  ln_epilogue(accO, b2, X, 0xFFFFFFFFu, g, beta, OUT, r0, lane);
}

extern "C" void kernel_launch(void* const* d_in, const int* in_sizes, int n_in,
                              void* d_out, int out_size, void* d_ws, size_t ws_size,
                              hipStream_t stream){
  (void)in_sizes; (void)n_in; (void)out_size; (void)ws_size;
  const float* feat = (const float*)d_in[0];
  const float* Ipts = (const float*)d_in[1];
  const float* Wq   = (const float*)d_in[2];
  const float* Wk   = (const float*)d_in[3];
  const float* Wv   = (const float*)d_in[4];
  const float* Wo   = (const float*)d_in[5];
  const float* W1   = (const float*)d_in[6];
  const float* b1   = (const float*)d_in[7];
  const float* W2   = (const float*)d_in[8];
  const float* b2   = (const float*)d_in[9];
  const float* g1   = (const float*)d_in[10];
  const float* be1  = (const float*)d_in[11];
  const float* g2   = (const float*)d_in[12];
  const float* be2  = (const float*)d_in[13];
  float* out = (float*)d_out;

  float* bigA   = (float*)d_ws;                 // 64 MiB: St (A) / Q,x1 (B)
  float* bigB   = bigA + (size_t)BN*128;        // 64 MiB: V (A) / attn-out (B)
  float* wfused = bigB + (size_t)BN*128;        // 16384
  float* Oind   = wfused + 16384;               // BM*128
  float* x1ind  = Oind   + BM*128;
  float* Hind   = x1ind  + BM*128;
  float* Khb    = Hind   + BM*128;
  float* Vhb    = Khb    + BM*128;

  for (int l = 0; l < LL; l++){
    const float* x = (l == 0) ? feat : out;
    const float* Il = Ipts + l*MM*DD;
    int j0 = l*2, j1 = l*2 + 1;
    // ---- phase A: H = MAB(I, x) ----
    prep_phaseA<<<1, 256, 0, stream>>>(Il, Wq + j0*16384, Wk + j0*16384, wfused);
    gemm128_plain<<<BN/128, 512, 0, stream>>>(x, wfused, bigA, BN);          // St = x @ Wf
    gemm128_plain<<<BN/128, 512, 0, stream>>>(x, Wv + j0*16384, bigB, BN);   // V
    attn_ind<<<BB*HH, 1024, 0, stream>>>(bigA, bigB, Oind);
    gemm128_ln<<<BM/128, 512, 0, stream>>>(Oind, Wo + j0*16384, nullptr, Il, 31u,
                                           g1 + j0*128, be1 + j0*128, x1ind, BM);
    ffn_fused<<<BM/128, 512, 0, stream>>>(x1ind, W1 + j0*65536, b1 + j0*512,
                                          W2 + j0*65536, b2 + j0*128,
                                          g2 + j0*128, be2 + j0*128, Hind, BM);
    // ---- phase B: x = MAB(x, H) ----
    gemm128_plain<<<BN/128, 512, 0, stream>>>(x, Wq + j1*16384, bigA, BN);   // Q
    gemm128_plain<<<BM/128, 512, 0, stream>>>(Hind, Wk + j1*16384, Khb, BM);
    gemm128_plain<<<BM/128, 512, 0, stream>>>(Hind, Wv + j1*16384, Vhb, BM);
    attn_b<<<BB*32, 256, 0, stream>>>(bigA, Khb, Vhb, bigB);
    gemm128_ln<<<BN/128, 512, 0, stream>>>(bigB, Wo + j1*16384, nullptr, x, (unsigned)(BN-1),
                                           g1 + j1*128, be1 + j1*128, bigA, BN);
    ffn_fused<<<BN/128, 512, 0, stream>>>(bigA, W1 + j1*65536, b1 + j1*512,
                                          W2 + j1*65536, b2 + j1*128,
                                          g2 + j1*128, be2 + j1*128, out, BN);
  }
}

// Round 5
// 965.969 us; speedup vs baseline: 1.8634x; 1.3890x over previous
//
#include <hip/hip_runtime.h>
#include <hip/hip_bf16.h>

// SetTransEncoder: B=64, N=2048, M=32, D=128, H=4, DH=32, DFF=512, L=2
#define BB 64
#define NN 2048
#define MM 32
#define DD 128
#define HH 4
#define LL 2
#define BN (BB*NN)   // 131072 rows
#define BM (BB*MM)   // 2048 rows

typedef short bf16x8 __attribute__((ext_vector_type(8)));
typedef float f32x4 __attribute__((ext_vector_type(4)));
#define MFMA __builtin_amdgcn_mfma_f32_16x16x32_bf16

__device__ __forceinline__ unsigned short f2bf(float f){
  union { float f; unsigned int u; } v; v.f = f;
  unsigned int r = 0x7FFFu + ((v.u >> 16) & 1u);
  return (unsigned short)((v.u + r) >> 16);
}
__device__ __forceinline__ float bf2f(short u){
  union { unsigned int u; float f; } v; v.u = ((unsigned int)(unsigned short)u) << 16; return v.f;
}

__device__ __forceinline__ bf16x8 cvt8(const float* __restrict__ p){
  float4 a = *reinterpret_cast<const float4*>(p);
  float4 b = *reinterpret_cast<const float4*>(p + 4);
  bf16x8 r;
  r[0]=(short)f2bf(a.x); r[1]=(short)f2bf(a.y); r[2]=(short)f2bf(a.z); r[3]=(short)f2bf(a.w);
  r[4]=(short)f2bf(b.x); r[5]=(short)f2bf(b.y); r[6]=(short)f2bf(b.z); r[7]=(short)f2bf(b.w);
  return r;
}

// ---- weight image staging: img holds the EXACT 32KB LDS byte image ----
// (bf16, [c][k] transposed, XOR-swizzled). Stage = linear copy, zero conflicts.
__device__ __forceinline__ void stage_img(const unsigned short* __restrict__ img,
                                          unsigned short* Wt){
  int wave = threadIdx.x >> 6, lane = threadIdx.x & 63;
#if defined(__has_builtin) && __has_builtin(__builtin_amdgcn_global_load_lds)
  #pragma unroll
  for (int i = 0; i < 8; i++){
    int off = ((i*4 + wave) << 9);            // ushort offset: (i*4+wave)*1024B
    const unsigned short* gp = img + off + lane*8;
    unsigned short* lp = Wt + off;            // wave-uniform LDS base
    __builtin_amdgcn_global_load_lds(
        (__attribute__((address_space(1))) void*)gp,
        (__attribute__((address_space(3))) void*)lp, 16, 0, 0);
  }
#else
  int t = threadIdx.x;
  #pragma unroll
  for (int i = 0; i < 8; i++){
    int off8 = (t + i*256) * 8;
    *reinterpret_cast<bf16x8*>(Wt + off8) =
        *reinterpret_cast<const bf16x8*>(img + off8);
  }
#endif
}

__device__ __forceinline__ bf16x8 bfrag(const unsigned short* Wt, int cb, int k0, int lane){
  int c = (cb << 4) + (lane & 15);
  int kk = (k0 + ((lane >> 4) << 3)) ^ ((c & 7) << 3);
  return *reinterpret_cast<const bf16x8*>(Wt + (c << 7) + kk);
}

// A-fragment loaders: 32 rows per wave (2 subtiles of 16)
__device__ __forceinline__ void load_afrag_f32(const float* __restrict__ A, int r0, int lane,
                                               bf16x8 af[2][4]){
  int li = lane & 15, lg = lane >> 4;
  #pragma unroll
  for (int s = 0; s < 2; s++){
    const float* ap = A + (size_t)(r0 + s*16 + li) * 128 + (lg << 3);
    #pragma unroll
    for (int ks = 0; ks < 4; ks++) af[s][ks] = cvt8(ap + ks*32);
  }
}
__device__ __forceinline__ void load_afrag_bf16(const unsigned short* __restrict__ A, int r0,
                                                int lane, bf16x8 af[2][4]){
  int li = lane & 15, lg = lane >> 4;
  #pragma unroll
  for (int s = 0; s < 2; s++){
    const unsigned short* ap = A + (size_t)(r0 + s*16 + li) * 128 + (lg << 3);
    #pragma unroll
    for (int ks = 0; ks < 4; ks++) af[s][ks] = *reinterpret_cast<const bf16x8*>(ap + ks*32);
  }
}

__device__ __forceinline__ void mfma_tile32(const bf16x8 af[2][4], const unsigned short* Wt,
                                            int lane, f32x4 acc[2][8]){
  #pragma unroll
  for (int ks = 0; ks < 4; ks++){
    #pragma unroll
    for (int cb = 0; cb < 8; cb++){
      bf16x8 b = bfrag(Wt, cb, ks*32, lane);
      acc[0][cb] = MFMA(af[0][ks], b, acc[0][cb], 0, 0, 0);
      acc[1][cb] = MFMA(af[1][ks], b, acc[1][cb], 0, 0, 0);
    }
  }
}

__device__ __forceinline__ void zero_acc(f32x4 acc[2][8]){
  #pragma unroll
  for (int s = 0; s < 2; s++)
    #pragma unroll
    for (int cb = 0; cb < 8; cb++) acc[s][cb] = (f32x4){0.f,0.f,0.f,0.f};
}

__device__ __forceinline__ void store_f32(const f32x4 acc[2][8], float* __restrict__ C,
                                          int r0, int lane){
  int li = lane & 15, lg = lane >> 4;
  #pragma unroll
  for (int s = 0; s < 2; s++)
    #pragma unroll
    for (int q = 0; q < 4; q++){
      float* crow = C + (size_t)(r0 + s*16 + lg*4 + q) * 128;
      #pragma unroll
      for (int cb = 0; cb < 8; cb++) crow[cb*16 + li] = acc[s][cb][q];
    }
}
__device__ __forceinline__ void store_bf16(const f32x4 acc[2][8], unsigned short* __restrict__ C,
                                           int r0, int lane){
  int li = lane & 15, lg = lane >> 4;
  #pragma unroll
  for (int s = 0; s < 2; s++)
    #pragma unroll
    for (int q = 0; q < 4; q++){
      unsigned short* crow = C + (size_t)(r0 + s*16 + lg*4 + q) * 128;
      #pragma unroll
      for (int cb = 0; cb < 8; cb++) crow[cb*16 + li] = f2bf(acc[s][cb][q]);
    }
}

// LayerNorm epilogue over one 16-row subtile.
__device__ __forceinline__ void ln_epilogue(const f32x4 acc[8], const float* __restrict__ bias,
    const float* __restrict__ resid, unsigned int resmask,
    const float* __restrict__ g, const float* __restrict__ beta,
    float* __restrict__ C, int r0, int lane){
  int li = lane & 15, lg = lane >> 4;
  float gv[8], bv[8], biasv[8];
  #pragma unroll
  for (int cb = 0; cb < 8; cb++){
    int col = cb*16 + li;
    gv[cb] = g[col]; bv[cb] = beta[col];
    biasv[cb] = bias ? bias[col] : 0.f;
  }
  #pragma unroll
  for (int q = 0; q < 4; q++){
    int r = r0 + lg*4 + q;
    const float* rrow = resid + (size_t)(r & resmask) * 128;
    float v[8], sum = 0.f, ss = 0.f;
    #pragma unroll
    for (int cb = 0; cb < 8; cb++){
      float x = acc[cb][q] + biasv[cb] + rrow[cb*16 + li];
      v[cb] = x; sum += x; ss += x*x;
    }
    #pragma unroll
    for (int mk = 1; mk < 16; mk <<= 1){ sum += __shfl_xor(sum, mk); ss += __shfl_xor(ss, mk); }
    float mu = sum * (1.f/128.f);
    float var = ss * (1.f/128.f) - mu*mu;
    float rs = rsqrtf(var + 1e-5f);
    float* crow = C + (size_t)r * 128;
    #pragma unroll
    for (int cb = 0; cb < 8; cb++)
      crow[cb*16 + li] = (v[cb] - mu) * rs * gv[cb] + bv[cb];
  }
}

// ---------------- kernels ----------------

// Convert all standard weights to bf16 swizzled LDS images (48 slots of 16384).
__global__ __launch_bounds__(256) void prep_imgs(const float* __restrict__ Wq,
    const float* __restrict__ Wk, const float* __restrict__ Wv, const float* __restrict__ Wo,
    const float* __restrict__ W1, const float* __restrict__ W2, unsigned short* __restrict__ imgs){
  int slot = blockIdx.x;
  const float* src; int ldw;
  if (slot < 16){
    int j = slot >> 2, m = slot & 3;
    const float* base = (m==0) ? Wq : (m==1) ? Wk : (m==2) ? Wv : Wo;
    src = base + j*16384; ldw = 128;
  } else if (slot < 32){
    int s = slot - 16; int j = s >> 2, dc = s & 3;
    src = W1 + j*65536 + dc*128; ldw = 512;
  } else {
    int s = slot - 32; int j = s >> 2, dc = s & 3;
    src = W2 + j*65536 + dc*16384; ldw = 128;
  }
  unsigned short* img = imgs + (size_t)slot * 16384;
  for (int i = threadIdx.x; i < 16384; i += 256){
    int k = i >> 7, c = i & 127;
    img[(c << 7) + (k ^ ((c & 7) << 3))] = f2bf(src[k*ldw + c]);
  }
}

// Qi = I @ Wq; WfImg[k][c] = bf16(scale * sum_d Wk[k][hc*32+d] * Qi[qc][hc*32+d])
// grid=16, each block does 8 k-rows (Qi recomputed redundantly, tiny).
__global__ __launch_bounds__(256) void prep_phaseA(const float* __restrict__ I,
    const float* __restrict__ Wq, const float* __restrict__ Wk, unsigned short* __restrict__ WfImg){
  __shared__ float Qi[32*128];
  for (int i = threadIdx.x; i < 4096; i += 256){
    int q = i >> 7, c = i & 127;
    float s = 0.f;
    #pragma unroll 8
    for (int d = 0; d < 128; d++) s += I[q*128 + d] * Wq[d*128 + c];
    Qi[i] = s;
  }
  __syncthreads();
  const float scale = 0.17677669529663687f; // 1/sqrt(32)
  for (int i = threadIdx.x; i < 1024; i += 256){
    int k = (blockIdx.x << 3) + (i >> 7), c = i & 127;
    int hc = c >> 5, qc = c & 31;
    float s = 0.f;
    #pragma unroll
    for (int d = 0; d < 32; d++) s += Wk[k*128 + hc*32 + d] * Qi[qc*128 + hc*32 + d];
    WfImg[(c << 7) + (k ^ ((c & 7) << 3))] = f2bf(s * scale);
  }
}

// dual GEMM: St = X@W0 (fp32), V = X@W1 (bf16); shared A-fragments.
__global__ __launch_bounds__(256) void gemm_dual(const float* __restrict__ X,
    const unsigned short* __restrict__ img0, const unsigned short* __restrict__ img1,
    float* __restrict__ St, unsigned short* __restrict__ Vb){
  __shared__ __align__(16) unsigned short W0[16384];
  __shared__ __align__(16) unsigned short W1s[16384];
  stage_img(img0, W0);
  stage_img(img1, W1s);
  __syncthreads();
  int lane = threadIdx.x & 63, wave = threadIdx.x >> 6;
  int r0 = blockIdx.x*128 + wave*32;
  bf16x8 af[2][4];
  load_afrag_f32(X, r0, lane, af);
  f32x4 acc[2][8];
  zero_acc(acc);
  mfma_tile32(af, W0, lane, acc);
  store_f32(acc, St, r0, lane);
  zero_acc(acc);
  mfma_tile32(af, W1s, lane, acc);
  store_bf16(acc, Vb, r0, lane);
}

// plain GEMM (fp32 A, fp32 out) via image
__global__ __launch_bounds__(256) void gemm_img(const float* __restrict__ A,
    const unsigned short* __restrict__ img, float* __restrict__ C){
  __shared__ __align__(16) unsigned short Wt[16384];
  stage_img(img, Wt);
  __syncthreads();
  int lane = threadIdx.x & 63, wave = threadIdx.x >> 6;
  int r0 = blockIdx.x*128 + wave*32;
  bf16x8 af[2][4];
  load_afrag_f32(A, r0, lane, af);
  f32x4 acc[2][8];
  zero_acc(acc);
  mfma_tile32(af, Wt, lane, acc);
  store_f32(acc, C, r0, lane);
}

// GEMM + LN epilogue, fp32 A
__global__ __launch_bounds__(256) void gemm_ln_f32A(const float* __restrict__ A,
    const unsigned short* __restrict__ img, const float* __restrict__ resid, unsigned int resmask,
    const float* __restrict__ g, const float* __restrict__ beta, float* __restrict__ C){
  __shared__ __align__(16) unsigned short Wt[16384];
  stage_img(img, Wt);
  __syncthreads();
  int lane = threadIdx.x & 63, wave = threadIdx.x >> 6;
  int r0 = blockIdx.x*128 + wave*32;
  bf16x8 af[2][4];
  load_afrag_f32(A, r0, lane, af);
  f32x4 acc[2][8];
  zero_acc(acc);
  mfma_tile32(af, Wt, lane, acc);
  ln_epilogue(acc[0], nullptr, resid, resmask, g, beta, C, r0,      lane);
  ln_epilogue(acc[1], nullptr, resid, resmask, g, beta, C, r0 + 16, lane);
}

// GEMM + LN epilogue, bf16 A
__global__ __launch_bounds__(256) void gemm_ln_bf16A(const unsigned short* __restrict__ A,
    const unsigned short* __restrict__ img, const float* __restrict__ resid,
    const float* __restrict__ g, const float* __restrict__ beta, float* __restrict__ C){
  __shared__ __align__(16) unsigned short Wt[16384];
  stage_img(img, Wt);
  __syncthreads();
  int lane = threadIdx.x & 63, wave = threadIdx.x >> 6;
  int r0 = blockIdx.x*128 + wave*32;
  bf16x8 af[2][4];
  load_afrag_bf16(A, r0, lane, af);
  f32x4 acc[2][8];
  zero_acc(acc);
  mfma_tile32(af, Wt, lane, acc);
  ln_epilogue(acc[0], nullptr, resid, 0xFFFFFFFFu, g, beta, C, r0,      lane);
  ln_epilogue(acc[1], nullptr, resid, 0xFFFFFFFFu, g, beta, C, r0 + 16, lane);
}

// induced attention: column softmax over St[b, j, h*32+q] fused with PV (V bf16).
__global__ __launch_bounds__(1024) void attn_ind(const float* __restrict__ St,
    const unsigned short* __restrict__ V, float* __restrict__ O){
  int b = blockIdx.x >> 2, h = blockIdx.x & 3;
  int q = threadIdx.x & 31;
  int gg = threadIdx.x >> 5;
  int lane = threadIdx.x & 63;
  int wave = threadIdx.x >> 6;
  float m = -1e30f, s = 0.f;
  float o[32];
  #pragma unroll
  for (int d = 0; d < 32; d++) o[d] = 0.f;
  const float* Sb = St + (size_t)b*NN*128 + h*32 + q;
  const unsigned short* Vb = V + (size_t)b*NN*128 + h*32;
  for (int j = gg; j < NN; j += 32){
    float sv = Sb[(size_t)j*128];
    float p;
    if (sv > m){
      float f = __expf(m - sv);
      s *= f;
      #pragma unroll
      for (int d = 0; d < 32; d++) o[d] *= f;
      m = sv; p = 1.f;
    } else {
      p = __expf(sv - m);
    }
    s += p;
    const bf16x8* vr = reinterpret_cast<const bf16x8*>(Vb + (size_t)j*128);
    #pragma unroll
    for (int g4 = 0; g4 < 4; g4++){
      bf16x8 vv = vr[g4];
      #pragma unroll
      for (int e = 0; e < 8; e++) o[g4*8+e] += p * bf2f(vv[e]);
    }
  }
  {
    float m2 = __shfl_xor(m, 32);
    float s2 = __shfl_xor(s, 32);
    float mn = fmaxf(m, m2);
    float f1 = __expf(m - mn), f2 = __expf(m2 - mn);
    s = s*f1 + s2*f2;
    #pragma unroll
    for (int d = 0; d < 32; d++){
      float o2 = __shfl_xor(o[d], 32);
      o[d] = o[d]*f1 + o2*f2;
    }
    m = mn;
  }
  __shared__ float red[16][32][34];
  if (lane < 32){
    red[wave][q][0] = m;
    red[wave][q][1] = s;
    #pragma unroll
    for (int d = 0; d < 32; d++) red[wave][q][2+d] = o[d];
  }
  __syncthreads();
  if (threadIdx.x < 32){
    int qq = threadIdx.x;
    float mm = red[0][qq][0], ssum = red[0][qq][1];
    float oo[32];
    #pragma unroll
    for (int d = 0; d < 32; d++) oo[d] = red[0][qq][2+d];
    for (int w = 1; w < 16; w++){
      float m2 = red[w][qq][0], s2 = red[w][qq][1];
      float mn = fmaxf(mm, m2);
      float f1 = __expf(mm - mn), f2 = __expf(m2 - mn);
      ssum = ssum*f1 + s2*f2;
      #pragma unroll
      for (int d = 0; d < 32; d++) oo[d] = oo[d]*f1 + red[w][qq][2+d]*f2;
      mm = mn;
    }
    float inv = 1.f / ssum;
    float* op = O + (size_t)(b*MM + qq)*128 + h*32;
    #pragma unroll
    for (int d = 0; d < 32; d++) op[d] = oo[d]*inv;
  }
}

// phase-B fused: Q = X@Wq (MFMA) -> qs in LDS (scaled, bf16) -> per-row 32-key attention.
// K/V (fp32, BM-sized) staged to LDS. Output bf16. One block = 128 x-rows.
__global__ __launch_bounds__(256) void attn_qkv(const float* __restrict__ X,
    const unsigned short* __restrict__ WqImg, const float* __restrict__ Kh,
    const float* __restrict__ Vh, unsigned short* __restrict__ Obf){
  __shared__ __align__(16) unsigned short WtA[16384];   // Wq img, then reused as qs
  __shared__ __align__(16) float Ks[4096];
  __shared__ __align__(16) float Vs[4096];
  int b = blockIdx.x >> 4, rblk = blockIdx.x & 15;
  int grow0 = (b << 11) + (rblk << 7);
  stage_img(WqImg, WtA);
  for (int i = threadIdx.x*4; i < 4096; i += 1024){
    *reinterpret_cast<float4*>(&Ks[i]) = *reinterpret_cast<const float4*>(&Kh[(b<<12) + i]);
    *reinterpret_cast<float4*>(&Vs[i]) = *reinterpret_cast<const float4*>(&Vh[(b<<12) + i]);
  }
  __syncthreads();
  int lane = threadIdx.x & 63, wave = threadIdx.x >> 6;
  int li = lane & 15, lg = lane >> 4;
  bf16x8 af[2][4];
  load_afrag_f32(X, grow0 + wave*32, lane, af);
  f32x4 acc[2][8];
  zero_acc(acc);
  mfma_tile32(af, WtA, lane, acc);
  __syncthreads();                       // all waves done reading Wq image
  const float scale = 0.17677669529663687f;
  #pragma unroll
  for (int s = 0; s < 2; s++)
    #pragma unroll
    for (int q = 0; q < 4; q++){
      int rl = wave*32 + s*16 + lg*4 + q;
      #pragma unroll
      for (int cb = 0; cb < 8; cb++){
        int col = cb*16 + li;
        WtA[(rl << 7) + (col ^ ((rl & 7) << 3))] = f2bf(acc[s][cb][q] * scale);
      }
    }
  __syncthreads();
  int row = threadIdx.x & 127;
  int h0 = threadIdx.x >> 7;
  #pragma unroll
  for (int hh = 0; hh < 2; hh++){
    int h = h0 + hh*2;
    float qf[32];
    #pragma unroll
    for (int g4 = 0; g4 < 4; g4++){
      bf16x8 v = *reinterpret_cast<const bf16x8*>(&WtA[(row << 7) + ((h*32 + g4*8) ^ ((row & 7) << 3))]);
      #pragma unroll
      for (int e = 0; e < 8; e++) qf[g4*8+e] = bf2f(v[e]);
    }
    float sc[32], m = -1e30f;
    #pragma unroll
    for (int k = 0; k < 32; k++){
      float dot = 0.f;
      const float* kp = &Ks[(k << 7) + (h << 5)];
      #pragma unroll
      for (int d4 = 0; d4 < 8; d4++){
        float4 kv = reinterpret_cast<const float4*>(kp)[d4];
        dot += qf[d4*4]*kv.x + qf[d4*4+1]*kv.y + qf[d4*4+2]*kv.z + qf[d4*4+3]*kv.w;
      }
      sc[k] = dot; m = fmaxf(m, dot);
    }
    float den = 0.f;
    #pragma unroll
    for (int k = 0; k < 32; k++){ sc[k] = __expf(sc[k]-m); den += sc[k]; }
    float inv = 1.f/den;
    float o[32];
    #pragma unroll
    for (int d = 0; d < 32; d++) o[d] = 0.f;
    #pragma unroll
    for (int k = 0; k < 32; k++){
      float p = sc[k];
      const float* vp = &Vs[(k << 7) + (h << 5)];
      #pragma unroll
      for (int d4 = 0; d4 < 8; d4++){
        float4 vv = reinterpret_cast<const float4*>(vp)[d4];
        o[d4*4]   += p*vv.x; o[d4*4+1] += p*vv.y;
        o[d4*4+2] += p*vv.z; o[d4*4+3] += p*vv.w;
      }
    }
    unsigned short* op = Obf + (size_t)(grow0 + row)*128 + (h << 5);
    #pragma unroll
    for (int g4 = 0; g4 < 4; g4++){
      bf16x8 pk;
      #pragma unroll
      for (int e = 0; e < 8; e++) pk[e] = (short)f2bf(o[g4*8+e]*inv);
      *reinterpret_cast<bf16x8*>(op + g4*8) = pk;
    }
  }
}

// fused FFN via images: OUT = LN(X + relu(X@W1+b1)@W2 + b2)
__global__ __launch_bounds__(256) void ffn_img(const float* __restrict__ X,
    const unsigned short* __restrict__ W1i, const float* __restrict__ b1,
    const unsigned short* __restrict__ W2i, const float* __restrict__ b2,
    const float* __restrict__ g, const float* __restrict__ beta,
    float* __restrict__ OUT){
  __shared__ __align__(16) unsigned short Wt[16384];
  __shared__ __align__(16) unsigned short ht[16384];
  int lane = threadIdx.x & 63, wave = threadIdx.x >> 6;
  int li = lane & 15, lg = lane >> 4;
  int r0 = blockIdx.x*128 + wave*32;
  bf16x8 af[2][4];
  load_afrag_f32(X, r0, lane, af);
  f32x4 accO[2][8];
  zero_acc(accO);
  for (int dc = 0; dc < 4; dc++){
    __syncthreads();                     // prev-iter Wt/ht readers done
    stage_img(W1i + dc*16384, Wt);
    __syncthreads();
    f32x4 acc1[2][8];
    zero_acc(acc1);
    mfma_tile32(af, Wt, lane, acc1);
    #pragma unroll
    for (int s = 0; s < 2; s++)
      #pragma unroll
      for (int q = 0; q < 4; q++){
        int rl = wave*32 + s*16 + lg*4 + q;
        #pragma unroll
        for (int cb = 0; cb < 8; cb++){
          int col = cb*16 + li;
          float v = acc1[s][cb][q] + b1[dc*128 + col];
          v = fmaxf(v, 0.f);
          ht[(rl << 7) + (col ^ ((rl & 7) << 3))] = f2bf(v);
        }
      }
    __syncthreads();                     // Wt readers done + ht complete
    stage_img(W2i + dc*16384, Wt);
    __syncthreads();
    #pragma unroll
    for (int ks = 0; ks < 4; ks++){
      bf16x8 a[2];
      #pragma unroll
      for (int s = 0; s < 2; s++){
        int rl = wave*32 + s*16 + li;
        int kk = (ks*32 + (lg << 3)) ^ ((rl & 7) << 3);
        a[s] = *reinterpret_cast<const bf16x8*>(ht + (rl << 7) + kk);
      }
      #pragma unroll
      for (int cb = 0; cb < 8; cb++){
        bf16x8 bb = bfrag(Wt, cb, ks*32, lane);
        accO[0][cb] = MFMA(a[0], bb, accO[0][cb], 0, 0, 0);
        accO[1][cb] = MFMA(a[1], bb, accO[1][cb], 0, 0, 0);
      }
    }
  }
  ln_epilogue(accO[0], b2, X, 0xFFFFFFFFu, g, beta, OUT, r0,      lane);
  ln_epilogue(accO[1], b2, X, 0xFFFFFFFFu, g, beta, OUT, r0 + 16, lane);
}

extern "C" void kernel_launch(void* const* d_in, const int* in_sizes, int n_in,
                              void* d_out, int out_size, void* d_ws, size_t ws_size,
                              hipStream_t stream){
  (void)in_sizes; (void)n_in; (void)out_size; (void)ws_size;
  const float* feat = (const float*)d_in[0];
  const float* Ipts = (const float*)d_in[1];
  const float* Wq   = (const float*)d_in[2];
  const float* Wk   = (const float*)d_in[3];
  const float* Wv   = (const float*)d_in[4];
  const float* Wo   = (const float*)d_in[5];
  const float* W1   = (const float*)d_in[6];
  const float* b1   = (const float*)d_in[7];
  const float* W2   = (const float*)d_in[8];
  const float* b2   = (const float*)d_in[9];
  const float* g1   = (const float*)d_in[10];
  const float* be1  = (const float*)d_in[11];
  const float* g2   = (const float*)d_in[12];
  const float* be2  = (const float*)d_in[13];
  float* out = (float*)d_out;

  float* bigA = (float*)d_ws;                                   // BN*128 f32 (64MiB)
  unsigned short* bigV = (unsigned short*)(bigA + (size_t)BN*128); // BN*128 u16 (32MiB)
  float* Oind  = (float*)(bigV + (size_t)BN*128);               // BM*128 f32
  float* x1ind = Oind  + (size_t)BM*128;
  float* Hind  = x1ind + (size_t)BM*128;
  float* Khb   = Hind  + (size_t)BM*128;
  float* Vhb   = Khb   + (size_t)BM*128;
  unsigned short* imgs = (unsigned short*)(Vhb + (size_t)BM*128); // 50 slots x 16384

  unsigned short* imgQKVO = imgs;                 // slot (j*4+m), m: 0=Wq 1=Wk 2=Wv 3=Wo
  unsigned short* imgW1   = imgs + (size_t)16*16384;  // slot (j*4+dc)
  unsigned short* imgW2   = imgs + (size_t)32*16384;
  unsigned short* imgWf   = imgs + (size_t)48*16384;  // + l*16384

  prep_imgs<<<48, 256, 0, stream>>>(Wq, Wk, Wv, Wo, W1, W2, imgs);

  for (int l = 0; l < LL; l++){
    const float* x = (l == 0) ? feat : out;
    const float* Il = Ipts + l*MM*DD;
    int j0 = l*2, j1 = l*2 + 1;
    // ---- phase A: H = MAB(I, x) ----
    prep_phaseA<<<16, 256, 0, stream>>>(Il, Wq + j0*16384, Wk + j0*16384, imgWf + l*16384);
    gemm_dual<<<BN/128, 256, 0, stream>>>(x, imgWf + l*16384, imgQKVO + (j0*4+2)*16384,
                                          bigA, bigV);                 // St fp32, V bf16
    attn_ind<<<BB*HH, 1024, 0, stream>>>(bigA, bigV, Oind);
    gemm_ln_f32A<<<BM/128, 256, 0, stream>>>(Oind, imgQKVO + (j0*4+3)*16384, Il, 31u,
                                             g1 + j0*128, be1 + j0*128, x1ind);
    ffn_img<<<BM/128, 256, 0, stream>>>(x1ind, imgW1 + (size_t)j0*4*16384, b1 + j0*512,
                                        imgW2 + (size_t)j0*4*16384, b2 + j0*128,
                                        g2 + j0*128, be2 + j0*128, Hind);
    // ---- phase B: x = MAB(x, H) ----
    gemm_img<<<BM/128, 256, 0, stream>>>(Hind, imgQKVO + (j1*4+1)*16384, Khb);
    gemm_img<<<BM/128, 256, 0, stream>>>(Hind, imgQKVO + (j1*4+2)*16384, Vhb);
    attn_qkv<<<BN/128, 256, 0, stream>>>(x, imgQKVO + (j1*4+0)*16384, Khb, Vhb, bigV);
    gemm_ln_bf16A<<<BN/128, 256, 0, stream>>>(bigV, imgQKVO + (j1*4+3)*16384, x,
                                              g1 + j1*128, be1 + j1*128, bigA);
    ffn_img<<<BN/128, 256, 0, stream>>>(bigA, imgW1 + (size_t)j1*4*16384, b1 + j1*512,
                                        imgW2 + (size_t)j1*4*16384, b2 + j1*128,
                                        g2 + j1*128, be2 + j1*128, out);
  }
}